// Round 13
// baseline (528.250 us; speedup 1.0000x reference)
//
#include <hip/hip_runtime.h>
#include <hip/hip_bf16.h>

using bf16 = __hip_bfloat16;

typedef __attribute__((ext_vector_type(4))) float f32x4;
typedef __attribute__((ext_vector_type(8))) short short8;

typedef const void __attribute__((address_space(1)))* gas1_t;
typedef void __attribute__((address_space(3)))* las3_t;
#define GLDS(gp, lp) __builtin_amdgcn_global_load_lds((gas1_t)(gp), (las3_t)(lp), 16, 0, 0)

__device__ inline short f2bfbits(float f) {
  union { bf16 h; short s; } u;
  u.h = __float2bfloat16(f);
  return u.s;
}
__device__ inline float bf2f(short u) {
  unsigned x = ((unsigned)(unsigned short)u) << 16;
  float f; __builtin_memcpy(&f, &x, 4); return f;
}

__device__ inline void store_out(float* C, size_t idx, float v) { C[idx] = v; }
__device__ inline void store_out(bf16* C, size_t idx, float v) { C[idx] = __float2bfloat16(v); }

// ---------------------------------------------------------------------------
// 128x256 tile GEMM, BK=64 as 2 K-halves, 512 thr = 8 waves (2M x 4N),
// per-wave 64x64 out. Half-tile pipeline: ring of 4 half-slots per operand
// (A 4x8KB + B 4x16KB = 96KB). Per K-tile 2 phases; each phase: {stage one
// half-pair 6 phases ahead || 8 ds_read_b128 || 16 MFMA}; raw s_barrier,
// vmcnt(6) once per tile (2 newest half-pairs stay in flight — m201/T3+T4).
// Slot liveness: half (kt,ks) dead after phase ks barrier; stages target only
// dead slots (ring algebra verified). Chunk-XOR swizzle (conflicts = 0).
// C[m][n] = scale * sum_k A[m][k]*B[n][k]  (row-major operands, B^T layout)
// MODE 0: plain (QK proj / V proj), grid (bx, by).
// MODE 1: causal S: grid (272,1,4); by in [0,32) 128-row blocks, bx<=by>>1;
//         C -> 256-packed tri bf16 (block (by>>1, bx), half (by&1)).
// MODE 2: PV: A = 256-packed P, grid 512 1-D paired (per-CU K-sum const);
//         Klen = ((by>>1)+1)*256.
// ---------------------------------------------------------------------------
template<typename TOUT, int MODE>
__global__ __launch_bounds__(512, 2) void gemm8p(
    const short* __restrict__ A, int lda, size_t sAz,
    const short* __restrict__ B, int ldb, size_t sBz,
    TOUT* __restrict__ C, int ldc, size_t sCz,
    int K, float scale)
{
  int bx, by, z;
  if constexpr (MODE == 1) {
    const int i = blockIdx.x;
    int u = (int)((__builtin_sqrtf(4.f * (float)i + 1.f) - 1.f) * 0.5f);
    while (u > 0 && u * (u + 1) > i) u--;
    while ((u + 1) * (u + 2) <= i) u++;
    const int rem = i - u * (u + 1);
    if (rem < u + 1) { by = 2 * u; bx = rem; }
    else             { by = 2 * u + 1; bx = rem - (u + 1); }
    z = blockIdx.z;
  } else if constexpr (MODE == 2) {
    const int w = blockIdx.x;
    const int k = w >> 8, c = w & 255;
    bx = c & 3;
    const int h = c >> 2;            // [0,64)
    const int byb = h & 31, zb = h >> 5;
    by = k ? 31 - byb : byb;
    z = zb + 2 * k;
  } else {
    bx = blockIdx.x; by = blockIdx.y; z = 0;
  }
  const int u_rb = by >> 1;                      // packed 256-row block index
  const int tri_u = (u_rb * (u_rb + 1)) >> 1;

  const short* Az = A + (size_t)z * sAz;
  const short* Bz = B + (size_t)z * sBz;
  TOUT* Cz = C + (size_t)z * sCz;

  int Klen = K;
  if (MODE == 2) Klen = min(K, (u_rb + 1) * 256);
  const int NT = Klen >> 6;                      // 64-wide K-tiles (>= 4)

  __shared__ short As[4][128 * 32];              // 4 half-slots x 8 KB
  __shared__ short Bs[4][256 * 32];              // 4 half-slots x 16 KB

  const int t = threadIdx.x;
  const int lane = t & 63;
  const int wave = t >> 6;
  const int wm = wave >> 2;                      // 0..1 (64-row half of BM=128)
  const int wn = wave & 3;                       // 0..3 (64-col slice of BN=256)
  const int fr = lane & 15, kh = lane >> 4;
  const int koff = ((kh ^ ((fr >> 1) & 3)) << 3);  // swizzled 8-short chunk

  const int aro = (wm * 64 + fr) * 32;           // A read base (per m: +512)
  const int bro = (wn * 64 + fr) * 32;           // B read base (per n: +512)
  const int abase = by * 128;
  const int bbase = bx * 256;

  // staging source precompute (chunk-XOR pre-swizzled global column)
  const int s_row = t >> 2;                      // [0,128) for A
  const int s_sc = (((t & 3) ^ ((s_row >> 1) & 3)) << 3);

  f32x4 acc[4][4];
  #pragma unroll
  for (int i = 0; i < 4; i++)
    #pragma unroll
    for (int j = 0; j < 4; j++) acc[i][j] = (f32x4){0.f, 0.f, 0.f, 0.f};

  auto STAGE_A = [&](int kt, int ks) {           // 1 gload/thread (8 KB half)
    const int slot = (2 * kt + ks) & 3;
    const int k0 = kt * 64 + ks * 32;
    const short* pa;
    if constexpr (MODE == 2)
      pa = Az + (size_t)(tri_u + (k0 >> 8)) * 65536
              + (size_t)((by & 1) * 128 + s_row) * 256 + (k0 & 255) + s_sc;
    else
      pa = Az + (size_t)(abase + s_row) * lda + k0 + s_sc;
    GLDS(pa, (char*)&As[slot][0] + t * 16);
  };
  auto STAGE_B = [&](int kt, int ks) {           // 2 gloads/thread (16 KB half)
    const int slot = (2 * kt + ks) & 3;
    const int k0 = kt * 64 + ks * 32;
    #pragma unroll
    for (int j = 0; j < 2; j++) {
      const int e = j * 512 + t;
      const int row = e >> 2;
      const int sc = (((e & 3) ^ ((row >> 1) & 3)) << 3);
      const short* pb = Bz + (size_t)(bbase + row) * ldb + k0 + sc;
      GLDS(pb, (char*)&Bs[slot][0] + j * 8192 + t * 16);
    }
  };

  // prologue: stage tiles 0 and 1 fully (4 half-pairs, 12 loads)
  STAGE_A(0, 0); STAGE_B(0, 0);
  STAGE_A(0, 1); STAGE_B(0, 1);
  STAGE_A(1, 0); STAGE_B(1, 0);
  STAGE_A(1, 1); STAGE_B(1, 1);

  for (int kt = 0; kt < NT; kt++) {
    const short* as0 = &As[(2 * kt) & 3][0];
    const short* bs0 = &Bs[(2 * kt) & 3][0];
    const short* as1 = &As[(2 * kt + 1) & 3][0];
    const short* bs1 = &Bs[(2 * kt + 1) & 3][0];
    short8 af[4], bf[4];

    // ---- phase 1 (ks0): stage (kt+1,ks1) [6 phases ahead of its read] ----
    if (kt >= 1 && kt + 1 < NT) { STAGE_A(kt + 1, 1); STAGE_B(kt + 1, 1); }
    if (kt == NT - 1) asm volatile("s_waitcnt vmcnt(0)" ::: "memory");
    else              asm volatile("s_waitcnt vmcnt(6)" ::: "memory");
    __builtin_amdgcn_s_barrier();
    #pragma unroll
    for (int n = 0; n < 4; n++) bf[n] = *(const short8*)&bs0[bro + n * 512 + koff];
    #pragma unroll
    for (int m = 0; m < 4; m++) af[m] = *(const short8*)&as0[aro + m * 512 + koff];
    asm volatile("s_waitcnt lgkmcnt(0)" ::: "memory");
    __builtin_amdgcn_sched_barrier(0);
    __builtin_amdgcn_s_setprio(1);
    #pragma unroll
    for (int m = 0; m < 4; m++)
      #pragma unroll
      for (int n = 0; n < 4; n++)
        acc[m][n] = __builtin_amdgcn_mfma_f32_16x16x32_bf16(af[m], bf[n], acc[m][n], 0, 0, 0);
    __builtin_amdgcn_s_setprio(0);

    // ---- phase 2 (ks1): stage (kt+2,ks0) into slot freed by phase 1 ----
    __builtin_amdgcn_s_barrier();
    if (kt + 2 < NT) { STAGE_A(kt + 2, 0); STAGE_B(kt + 2, 0); }
    #pragma unroll
    for (int n = 0; n < 4; n++) bf[n] = *(const short8*)&bs1[bro + n * 512 + koff];
    #pragma unroll
    for (int m = 0; m < 4; m++) af[m] = *(const short8*)&as1[aro + m * 512 + koff];
    asm volatile("s_waitcnt lgkmcnt(0)" ::: "memory");
    __builtin_amdgcn_sched_barrier(0);
    __builtin_amdgcn_s_setprio(1);
    #pragma unroll
    for (int m = 0; m < 4; m++)
      #pragma unroll
      for (int n = 0; n < 4; n++)
        acc[m][n] = __builtin_amdgcn_mfma_f32_16x16x32_bf16(af[m], bf[n], acc[m][n], 0, 0, 0);
    __builtin_amdgcn_s_setprio(0);
    __builtin_amdgcn_s_barrier();
  }

  // C/D layout per frag: col = lane&15, row = (lane>>4)*4 + reg (m89-verified)
  #pragma unroll
  for (int m = 0; m < 4; m++)
    #pragma unroll
    for (int n = 0; n < 4; n++) {
      int col_l = wn * 64 + n * 16 + fr;
      #pragma unroll
      for (int r = 0; r < 4; r++) {
        int row_l = wm * 64 + m * 16 + kh * 4 + r;
        if constexpr (MODE == 1)
          store_out(Cz, (size_t)(tri_u + bx) * 65536
                        + (size_t)((by & 1) * 128 + row_l) * 256 + col_l,
                    acc[m][n][r] * scale);
        else
          store_out(Cz, (size_t)(by * 128 + row_l) * ldc + bx * 256 + col_l,
                    acc[m][n][r] * scale);
      }
    }
}

// fp32 -> bf16 elementwise convert with scale, 8 elems/thread/iter
__global__ __launch_bounds__(256) void cvt_bf16(
    const float* __restrict__ in, bf16* __restrict__ out, int n, float scale)
{
  for (int i = (blockIdx.x * 256 + threadIdx.x) * 8; i < n; i += gridDim.x * 2048) {
    f32x4 v0 = *(const f32x4*)&in[i];
    f32x4 v1 = *(const f32x4*)&in[i + 4];
    short8 o = { f2bfbits(v0[0] * scale), f2bfbits(v0[1] * scale),
                 f2bfbits(v0[2] * scale), f2bfbits(v0[3] * scale),
                 f2bfbits(v1[0] * scale), f2bfbits(v1[1] * scale),
                 f2bfbits(v1[2] * scale), f2bfbits(v1[3] * scale) };
    *(short8*)&out[i] = o;
  }
}

// In-place softmax on 256-packed block-triangular bf16 scores.
__global__ __launch_bounds__(256) void softmax_causal_packed(short* SP, int T)
{
  __shared__ float rowv[4096];
  __shared__ float red[4];
  const int r = blockIdx.x;
  const int z = blockIdx.y;
  const int rb = r >> 8, rl = r & 255;
  const size_t tri = (size_t)((rb * (rb + 1)) >> 1);
  short* base = SP + (size_t)z * 136 * 65536;
  const int L = r + 1;
  const int kend = (rb + 1) * 256;
  const int t = threadIdx.x;

  float lmax = -3.0e38f;
  for (int i = t * 8; i < kend; i += 2048) {
    short8 s = *(const short8*)(base + (tri + (i >> 8)) * 65536 + (size_t)rl * 256 + (i & 255));
    #pragma unroll
    for (int j = 0; j < 8; j++) {
      float v = bf2f(s[j]);
      rowv[i + j] = v;
      if (i + j < L) lmax = fmaxf(lmax, v);
    }
  }
  #pragma unroll
  for (int o = 32; o > 0; o >>= 1) lmax = fmaxf(lmax, __shfl_down(lmax, o));
  if ((t & 63) == 0) red[t >> 6] = lmax;
  __syncthreads();
  const float m = fmaxf(fmaxf(red[0], red[1]), fmaxf(red[2], red[3]));
  __syncthreads();

  float lsum = 0.f;
  for (int i = t; i < kend; i += 256) {
    float e = (i < L) ? __expf(rowv[i] - m) : 0.f;
    rowv[i] = e;
    lsum += e;
  }
  #pragma unroll
  for (int o = 32; o > 0; o >>= 1) lsum += __shfl_down(lsum, o);
  if ((t & 63) == 0) red[t >> 6] = lsum;
  __syncthreads();
  const float inv = 1.f / (red[0] + red[1] + red[2] + red[3]);

  for (int i = t * 8; i < kend; i += 2048) {
    short8 o;
    #pragma unroll
    for (int j = 0; j < 8; j++) o[j] = f2bfbits(rowv[i + j] * inv);
    *(short8*)(base + (tri + (i >> 8)) * 65536 + (size_t)rl * 256 + (i & 255)) = o;
  }
}

extern "C" void kernel_launch(void* const* d_in, const int* in_sizes, int n_in,
                              void* d_out, int out_size, void* d_ws, size_t ws_size,
                              hipStream_t stream) {
  (void)in_sizes; (void)n_in; (void)out_size; (void)ws_size;
  const float* X  = (const float*)d_in[0];   // (B,T,E)
  const float* Wq = (const float*)d_in[1];   // (A,E)
  const float* Wk = (const float*)d_in[2];
  const float* Wv = (const float*)d_in[3];
  float* Out = (float*)d_out;                // (B,T,A) fp32

  const int Bn = 4, T = 4096, E = 1024, Ad = 1024;
  const int M = Bn * T;  // 16384

  // workspace (peak ~164 MiB):
  //  [0,64Mi)   QKb : M x 2048 bf16 (Q | K interleaved per row)
  //  [64,96Mi)  Vt  : Ad x M bf16 (all-batch V^T; batch b at column b*T)
  //  [96,128Mi) Xb  : M x E bf16 (dead after projections)
  //  [128,134Mi) W  : Wqk (2048xE) + Wvb (AdxE) bf16 (dead after projections)
  //  [96Mi, +71.3MB) SP : 256-packed block-tri bf16, 4 x 136 x 256x256
  char* ws = (char*)d_ws;
  short* QKb = (short*)ws;
  short* Vt  = (short*)(ws + 67108864);
  short* Xb  = (short*)(ws + 100663296);
  short* Wqk = (short*)(ws + 134217728);
  short* Wvb = (short*)(ws + 138412032);
  short* SP  = (short*)(ws + 100663296);   // aliases Xb/W after projections

  dim3 blk(256), blk5(512);
  const float qscale = 0.03125f;  // 1/sqrt(1024)
  const size_t SPz = (size_t)136 * 65536;

  // one-time bf16 conversions (scale folded into Wq)
  cvt_bf16<<<dim3(8192), blk, 0, stream>>>(X, (bf16*)Xb, M * E, 1.0f);
  cvt_bf16<<<dim3(512),  blk, 0, stream>>>(Wq, (bf16*)Wqk, Ad * E, qscale);
  cvt_bf16<<<dim3(512),  blk, 0, stream>>>(Wk, (bf16*)(Wqk + (size_t)Ad * E), Ad * E, 1.0f);
  cvt_bf16<<<dim3(512),  blk, 0, stream>>>(Wv, (bf16*)Wvb, Ad * E, 1.0f);

  // fused Q|K projection: QKb (M x 2048) = Xb . Wqk^T   [1024 blocks]
  gemm8p<bf16, 0><<<dim3(2048 / 256, M / 128), blk5, 0, stream>>>(
      Xb, E, 0, Wqk, E, 0, (bf16*)QKb, 2048, 0, E, 1.0f);
  // all-batch V^T: Vt (Ad x M) = Wvb . Xb^T             [512 blocks]
  gemm8p<bf16, 0><<<dim3(M / 256, Ad / 128), blk5, 0, stream>>>(
      Wvb, E, 0, Xb, E, 0, (bf16*)Vt, M, 0, E, 1.0f);

  // S (256-packed, all batches): S = Q.K^T              [272 x 4 tri blocks]
  gemm8p<bf16, 1><<<dim3(272, 1, Bn), blk5, 0, stream>>>(
      QKb, 2048, (size_t)T * 2048,
      QKb + 1024, 2048, (size_t)T * 2048,
      (bf16*)SP, 256, SPz, Ad, 1.0f);

  // in-place softmax on packed scores (all batches)
  softmax_causal_packed<<<dim3(T, Bn), blk, 0, stream>>>(SP, T);

  // O = P.V (256-packed P; paired 1-D grid, per-CU K-sum constant)
  gemm8p<float, 2><<<dim3(512), blk5, 0, stream>>>(
      SP, 256, SPz,
      Vt, M, (size_t)T,
      Out, Ad, (size_t)T * Ad, T, 1.0f);
}

// Round 14
// 451.349 us; speedup vs baseline: 1.1704x; 1.1704x over previous
//
#include <hip/hip_runtime.h>
#include <hip/hip_bf16.h>

using bf16 = __hip_bfloat16;

typedef __attribute__((ext_vector_type(4))) float f32x4;
typedef __attribute__((ext_vector_type(8))) short short8;

typedef const void __attribute__((address_space(1)))* gas1_t;
typedef void __attribute__((address_space(3)))* las3_t;
#define GLDS(gp, lp) __builtin_amdgcn_global_load_lds((gas1_t)(gp), (las3_t)(lp), 16, 0, 0)

__device__ inline short f2bfbits(float f) {
  union { bf16 h; short s; } u;
  u.h = __float2bfloat16(f);
  return u.s;
}
__device__ inline float bf2f(short u) {
  unsigned x = ((unsigned)(unsigned short)u) << 16;
  float f; __builtin_memcpy(&f, &x, 4); return f;
}

__device__ inline void store_out(float* C, size_t idx, float v) { C[idx] = v; }
__device__ inline void store_out(bf16* C, size_t idx, float v) { C[idx] = __float2bfloat16(v); }

// ---------------------------------------------------------------------------
// 256x256 tile GEMM, BK=64, 512 thr = 8 waves (2M x 4N), per-wave 128x64.
// m201-discipline 4-phase K-tile: each phase {8 ds_read || stage 1 half-tile
// (2 gload_lds)} -> s_barrier -> lgkmcnt(0)+sched_barrier -> setprio+16 MFMA
// -> [counted vmcnt(8) at odd phases, wait-THEN-barrier so landing is global]
// -> s_barrier. Half-tiles (k-half granularity, 16KB) staged 6 phases ahead;
// double-buffered by tile parity; liveness: stage(s+1,k1)@r0 overwrites
// (s-1,k1) dead@4s-1; stage(s+2,k0)@r2 overwrites (s,k0) dead@4s+1.
// LINEAR LDS, NO source swizzle (swizzled-source variants measured FETCH
// 289MB vs 137MB linear — L2 poison; m198 hit 1167 TF with linear LDS).
// MODE 0: plain (QK proj, V proj).  MODE 1: causal S -> tri grid, C packed
// 256-block-tri bf16: block (by,bx) at (tri(by)+bx)*65536.
// ---------------------------------------------------------------------------
template<typename TOUT, int MODE>
__global__ __launch_bounds__(512) void gemm8(
    const short* __restrict__ A, int lda, size_t sAz,
    const short* __restrict__ B, int ldb, size_t sBz,
    TOUT* __restrict__ C, int ldc, size_t sCz,
    int K, float scale)
{
  int bx, by;
  if constexpr (MODE == 1) {
    const int i = blockIdx.x;
    by = (int)((__builtin_sqrtf(8.f * (float)i + 1.f) - 1.f) * 0.5f);
    if (((by * (by + 1)) >> 1) > i) by--;
    else if ((((by + 1) * (by + 2)) >> 1) <= i) by++;
    bx = i - ((by * (by + 1)) >> 1);
  } else {
    bx = blockIdx.x; by = blockIdx.y;
  }
  const int z = blockIdx.z;
  const int tri_by = (by * (by + 1)) >> 1;

  A += (size_t)z * sAz;
  B += (size_t)z * sBz;
  C += (size_t)z * sCz;

  const int NT = K >> 6;                       // 64-wide K-tiles (>= 2)

  __shared__ short AS[2][2][8192];             // [buf][k-half][256 rows x 32]
  __shared__ short BS[2][2][8192];

  const int t = threadIdx.x;
  const int lane = t & 63;
  const int wave = t >> 6;
  const int wm = wave >> 2;                    // 0..1 (128-row half)
  const int wn = wave & 3;                     // 0..3 (64-col slice)
  const int fr = lane & 15, kh = lane >> 4;

  f32x4 acc[8][4];
  #pragma unroll
  for (int i = 0; i < 8; i++)
    #pragma unroll
    for (int j = 0; j < 4; j++) acc[i][j] = (f32x4){0.f, 0.f, 0.f, 0.f};

  auto STAGE_A = [&](int tau, int h) {
    if (tau >= NT) return;
    const short* src = A + (size_t)(by * 256) * lda + tau * 64 + h * 32;
    char* dst = (char*)&AS[tau & 1][h][0] + wave * 1024;
    #pragma unroll
    for (int j = 0; j < 2; j++) {
      int e = j * 512 + t;
      GLDS(src + (size_t)(e >> 2) * lda + (e & 3) * 8, dst + j * 8192);
    }
  };
  auto STAGE_B = [&](int tau, int h) {
    if (tau >= NT) return;
    const short* src = B + (size_t)(bx * 256) * ldb + tau * 64 + h * 32;
    char* dst = (char*)&BS[tau & 1][h][0] + wave * 1024;
    #pragma unroll
    for (int j = 0; j < 2; j++) {
      int e = j * 512 + t;
      GLDS(src + (size_t)(e >> 2) * ldb + (e & 3) * 8, dst + j * 8192);
    }
  };

  // prologue: (0,Ak0)(0,Bk0)(0,Ak1)(0,Bk1)(1,Ak0)(1,Bk0); wait 2 oldest halves
  STAGE_A(0, 0); STAGE_B(0, 0);
  STAGE_A(0, 1); STAGE_B(0, 1);
  STAGE_A(1, 0); STAGE_B(1, 0);
  asm volatile("s_waitcnt vmcnt(8)" ::: "memory");
  __builtin_amdgcn_s_barrier();
  __builtin_amdgcn_sched_barrier(0);

  for (int s = 0; s < NT; s++) {
    const int buf = s & 1;
    #pragma unroll
    for (int r = 0; r < 4; r++) {
      const int kh2 = r >> 1, mh = r & 1;
      short8 af[4], bfr[4];
      #pragma unroll
      for (int n = 0; n < 4; n++)
        bfr[n] = *(const short8*)&BS[buf][kh2][(wn * 64 + n * 16 + fr) * 32 + kh * 8];
      #pragma unroll
      for (int m2 = 0; m2 < 4; m2++)
        af[m2] = *(const short8*)&AS[buf][kh2][(wm * 128 + mh * 64 + m2 * 16 + fr) * 32 + kh * 8];

      if      (r == 0) STAGE_A(s + 1, 1);
      else if (r == 1) STAGE_B(s + 1, 1);
      else if (r == 2) STAGE_A(s + 2, 0);
      else             STAGE_B(s + 2, 0);

      __builtin_amdgcn_s_barrier();
      asm volatile("s_waitcnt lgkmcnt(0)" ::: "memory");
      __builtin_amdgcn_sched_barrier(0);
      __builtin_amdgcn_s_setprio(1);
      #pragma unroll
      for (int m2 = 0; m2 < 4; m2++)
        #pragma unroll
        for (int n = 0; n < 4; n++)
          acc[mh * 4 + m2][n] =
              __builtin_amdgcn_mfma_f32_16x16x32_bf16(af[m2], bfr[n], acc[mh * 4 + m2][n], 0, 0, 0);
      __builtin_amdgcn_s_setprio(0);
      __builtin_amdgcn_sched_barrier(0);

      // counted wait BEFORE the phase-end barrier -> landing is global
      if (r == 1) {
        if (s + 1 < NT) asm volatile("s_waitcnt vmcnt(8)" ::: "memory");
        else            asm volatile("s_waitcnt vmcnt(0)" ::: "memory");
      } else if (r == 3) {
        if (s + 2 < NT) asm volatile("s_waitcnt vmcnt(8)" ::: "memory");
        else            asm volatile("s_waitcnt vmcnt(0)" ::: "memory");
      }
      __builtin_amdgcn_s_barrier();
      __builtin_amdgcn_sched_barrier(0);
    }
  }

  // C/D layout per frag: col = lane&15, row = (lane>>4)*4 + reg (m89-verified)
  #pragma unroll
  for (int m = 0; m < 8; m++)
    #pragma unroll
    for (int n = 0; n < 4; n++) {
      int col_l = wn * 64 + n * 16 + fr;
      #pragma unroll
      for (int r_ = 0; r_ < 4; r_++) {
        int row_l = wm * 128 + m * 16 + kh * 4 + r_;
        if constexpr (MODE == 1)
          store_out(C, (size_t)(tri_by + bx) * 65536 + (size_t)row_l * 256 + col_l,
                    acc[m][n][r_] * scale);
        else
          store_out(C, (size_t)(by * 256 + row_l) * ldc + bx * 256 + col_l,
                    acc[m][n][r_] * scale);
      }
    }
}

// ---------------------------------------------------------------------------
// PV: 128x128 tile, BK=32, 256 thr, round-3 proven loop (single buffer, plain
// __syncthreads, gload_lds, linear LDS, no swizzle). A = 256-packed tri P.
// 1-D paired grid (1024): co-resident blocks pair by with 31-by.
// ---------------------------------------------------------------------------
__global__ __launch_bounds__(256) void gemm_pv(
    const short* __restrict__ SP, const short* __restrict__ Vt,
    float* __restrict__ Out)
{
  const int w = blockIdx.x;
  const int c = w & 255, k = w >> 8;
  const int bx = c & 7;
  const int g = c >> 3;
  const int by = (k & 1) ? 31 - g : g;
  const int z = ((k & 1) << 1) | (k >> 1);

  const int u = by >> 1;                        // 256-row packed block
  const int tri_u = (u * (u + 1)) >> 1;
  const short* A = SP + (size_t)z * 136 * 65536;
  const int Klen = (u + 1) * 256;

  __shared__ short a_lds[128 * 32];
  __shared__ short b_lds[128 * 32];

  const int t = threadIdx.x;
  const int lane = t & 63;
  const int wave = t >> 6;
  const int wm = wave >> 1, wn = wave & 1;
  const int fr = lane & 15, kh = lane >> 4;

  f32x4 acc[4][4];
  #pragma unroll
  for (int i = 0; i < 4; i++)
    #pragma unroll
    for (int j = 0; j < 4; j++) acc[i][j] = (f32x4){0.f, 0.f, 0.f, 0.f};

  for (int k0 = 0; k0 < Klen; k0 += 32) {
    #pragma unroll
    for (int i = 0; i < 2; i++) {
      int e = i * 256 + t;
      int r_ = e >> 2, c_ = (e & 3) * 8;
      const short* pa = A + (size_t)(tri_u + (k0 >> 8)) * 65536
                          + (size_t)((by & 1) * 128 + r_) * 256 + (k0 & 255) + c_;
      const short* pb = Vt + (size_t)(bx * 128 + r_) * 16384 + z * 4096 + k0 + c_;
      GLDS(pa, (char*)a_lds + i * 4096 + wave * 1024);
      GLDS(pb, (char*)b_lds + i * 4096 + wave * 1024);
    }
    __syncthreads();

    short8 af[4], bfr[4];
    #pragma unroll
    for (int m = 0; m < 4; m++)
      af[m] = *(const short8*)&a_lds[(wm * 64 + m * 16 + fr) * 32 + kh * 8];
    #pragma unroll
    for (int n = 0; n < 4; n++)
      bfr[n] = *(const short8*)&b_lds[(wn * 64 + n * 16 + fr) * 32 + kh * 8];
    #pragma unroll
    for (int m = 0; m < 4; m++)
      #pragma unroll
      for (int n = 0; n < 4; n++)
        acc[m][n] = __builtin_amdgcn_mfma_f32_16x16x32_bf16(af[m], bfr[n], acc[m][n], 0, 0, 0);
    __syncthreads();
  }

  float* Cz = Out + (size_t)z * 4096 * 1024;
  #pragma unroll
  for (int m = 0; m < 4; m++)
    #pragma unroll
    for (int n = 0; n < 4; n++) {
      int col_l = wn * 64 + n * 16 + fr;
      #pragma unroll
      for (int r_ = 0; r_ < 4; r_++) {
        int row_l = wm * 64 + m * 16 + kh * 4 + r_;
        Cz[(size_t)(by * 128 + row_l) * 1024 + bx * 128 + col_l] = acc[m][n][r_];
      }
    }
}

// fp32 -> bf16 elementwise convert with scale, 8 elems/thread/iter
__global__ __launch_bounds__(256) void cvt_bf16(
    const float* __restrict__ in, bf16* __restrict__ out, int n, float scale)
{
  for (int i = (blockIdx.x * 256 + threadIdx.x) * 8; i < n; i += gridDim.x * 2048) {
    f32x4 v0 = *(const f32x4*)&in[i];
    f32x4 v1 = *(const f32x4*)&in[i + 4];
    short8 o = { f2bfbits(v0[0] * scale), f2bfbits(v0[1] * scale),
                 f2bfbits(v0[2] * scale), f2bfbits(v0[3] * scale),
                 f2bfbits(v1[0] * scale), f2bfbits(v1[1] * scale),
                 f2bfbits(v1[2] * scale), f2bfbits(v1[3] * scale) };
    *(short8*)&out[i] = o;
  }
}

// In-place softmax on 256-packed block-triangular bf16 scores.
__global__ __launch_bounds__(256) void softmax_causal_packed(short* SP, int T)
{
  __shared__ float rowv[4096];
  __shared__ float red[4];
  const int r = blockIdx.x;
  const int z = blockIdx.y;
  const int rb = r >> 8, rl = r & 255;
  const size_t tri = (size_t)((rb * (rb + 1)) >> 1);
  short* base = SP + (size_t)z * 136 * 65536;
  const int L = r + 1;
  const int kend = (rb + 1) * 256;
  const int t = threadIdx.x;

  float lmax = -3.0e38f;
  for (int i = t * 8; i < kend; i += 2048) {
    short8 s = *(const short8*)(base + (tri + (i >> 8)) * 65536 + (size_t)rl * 256 + (i & 255));
    #pragma unroll
    for (int j = 0; j < 8; j++) {
      float v = bf2f(s[j]);
      rowv[i + j] = v;
      if (i + j < L) lmax = fmaxf(lmax, v);
    }
  }
  #pragma unroll
  for (int o = 32; o > 0; o >>= 1) lmax = fmaxf(lmax, __shfl_down(lmax, o));
  if ((t & 63) == 0) red[t >> 6] = lmax;
  __syncthreads();
  const float m = fmaxf(fmaxf(red[0], red[1]), fmaxf(red[2], red[3]));
  __syncthreads();

  float lsum = 0.f;
  for (int i = t; i < kend; i += 256) {
    float e = (i < L) ? __expf(rowv[i] - m) : 0.f;
    rowv[i] = e;
    lsum += e;
  }
  #pragma unroll
  for (int o = 32; o > 0; o >>= 1) lsum += __shfl_down(lsum, o);
  if ((t & 63) == 0) red[t >> 6] = lsum;
  __syncthreads();
  const float inv = 1.f / (red[0] + red[1] + red[2] + red[3]);

  for (int i = t * 8; i < kend; i += 2048) {
    short8 o;
    #pragma unroll
    for (int j = 0; j < 8; j++) o[j] = f2bfbits(rowv[i + j] * inv);
    *(short8*)(base + (tri + (i >> 8)) * 65536 + (size_t)rl * 256 + (i & 255)) = o;
  }
}

extern "C" void kernel_launch(void* const* d_in, const int* in_sizes, int n_in,
                              void* d_out, int out_size, void* d_ws, size_t ws_size,
                              hipStream_t stream) {
  (void)in_sizes; (void)n_in; (void)out_size; (void)ws_size;
  const float* X  = (const float*)d_in[0];   // (B,T,E)
  const float* Wq = (const float*)d_in[1];   // (A,E)
  const float* Wk = (const float*)d_in[2];
  const float* Wv = (const float*)d_in[3];
  float* Out = (float*)d_out;                // (B,T,A) fp32

  const int Bn = 4, T = 4096, E = 1024, Ad = 1024;
  const int M = Bn * T;  // 16384

  // workspace (peak ~172 MiB):
  //  [0,64Mi)   QKb : M x 2048 bf16 (Q | K interleaved per row)
  //  [64,96Mi)  Vt  : Ad x M bf16 (all-batch V^T; batch b at column b*T)
  //  [96,128Mi) Xb  : M x E bf16 (dead after projections)
  //  [128,134Mi) W  : Wqk (2048xE) + Wvb (AdxE) bf16 (dead after projections)
  //  [96Mi, +71.3MB) SP : 256-packed block-tri bf16, 4 x 136 x 256x256
  char* ws = (char*)d_ws;
  short* QKb = (short*)ws;
  short* Vt  = (short*)(ws + 67108864);
  short* Xb  = (short*)(ws + 100663296);
  short* Wqk = (short*)(ws + 134217728);
  short* Wvb = (short*)(ws + 138412032);
  short* SP  = (short*)(ws + 100663296);   // aliases Xb/W after projections

  dim3 blk(256), blk5(512);
  const float qscale = 0.03125f;  // 1/sqrt(1024)
  const size_t SPz = (size_t)136 * 65536;

  // one-time bf16 conversions (scale folded into Wq)
  cvt_bf16<<<dim3(8192), blk, 0, stream>>>(X, (bf16*)Xb, M * E, 1.0f);
  cvt_bf16<<<dim3(512),  blk, 0, stream>>>(Wq, (bf16*)Wqk, Ad * E, qscale);
  cvt_bf16<<<dim3(512),  blk, 0, stream>>>(Wk, (bf16*)(Wqk + (size_t)Ad * E), Ad * E, 1.0f);
  cvt_bf16<<<dim3(512),  blk, 0, stream>>>(Wv, (bf16*)Wvb, Ad * E, 1.0f);

  // fused Q|K projection: QKb (M x 2048) = Xb . Wqk^T   [grid 8 x 64]
  gemm8<bf16, 0><<<dim3(2048 / 256, M / 256), blk5, 0, stream>>>(
      Xb, E, 0, Wqk, E, 0, (bf16*)QKb, 2048, 0, E, 1.0f);
  // all-batch V^T: Vt (Ad x M) = Wvb . Xb^T             [grid 64 x 4]
  gemm8<bf16, 0><<<dim3(M / 256, Ad / 256), blk5, 0, stream>>>(
      Wvb, E, 0, Xb, E, 0, (bf16*)Vt, M, 0, E, 1.0f);

  // S (256-packed, all batches): S = Q.K^T              [tri grid 136 x 4]
  gemm8<bf16, 1><<<dim3(136, 1, Bn), blk5, 0, stream>>>(
      QKb, 2048, (size_t)T * 2048,
      QKb + 1024, 2048, (size_t)T * 2048,
      (bf16*)SP, 256, SPz, Ad, 1.0f);

  // in-place softmax on packed scores (all batches)
  softmax_causal_packed<<<dim3(T, Bn), blk, 0, stream>>>(SP, T);

  // O = P.V (256-packed P; 128^2 proven loop; paired 1-D grid 1024)
  gemm_pv<<<dim3(1024), blk, 0, stream>>>(SP, Vt, Out);
}

// Round 15
// 384.064 us; speedup vs baseline: 1.3754x; 1.1752x over previous
//
#include <hip/hip_runtime.h>
#include <hip/hip_bf16.h>

using bf16 = __hip_bfloat16;

typedef __attribute__((ext_vector_type(4))) float f32x4;
typedef __attribute__((ext_vector_type(8))) short short8;

typedef const void __attribute__((address_space(1)))* gas1_t;
typedef void __attribute__((address_space(3)))* las3_t;
#define GLDS(gp, lp) __builtin_amdgcn_global_load_lds((gas1_t)(gp), (las3_t)(lp), 16, 0, 0)

__device__ inline short f2bfbits(float f) {
  union { bf16 h; short s; } u;
  u.h = __float2bfloat16(f);
  return u.s;
}
__device__ inline float bf2f(short u) {
  unsigned x = ((unsigned)(unsigned short)u) << 16;
  float f; __builtin_memcpy(&f, &x, 4); return f;
}

__device__ inline void store_out(float* C, size_t idx, float v) { C[idx] = v; }
__device__ inline void store_out(bf16* C, size_t idx, float v) { C[idx] = __float2bfloat16(v); }

// ---------------------------------------------------------------------------
// ROUND-10 gemm256 VERBATIM (best measured total: 399us).
// 256x256 tile, BK=32, 512 thr = 8 waves (2M x 4N); 3-ring LDS + counted
// vmcnt(4); chunk-XOR swizzle both-sides.
// MODE 0: plain, identity raster.
// MODE 1: causal S -> tri grid, C to 256-packed tri bf16.
// MODE 2: PV -> A is 256-packed P, K limited to (by+1)*256.
// ---------------------------------------------------------------------------
template<typename TOUT, int MODE>
__global__ __launch_bounds__(512, 2) void gemm256(
    const short* __restrict__ A, int lda, size_t sAz,
    const short* __restrict__ B, int ldb, size_t sBz,
    TOUT* __restrict__ C, int ldc, size_t sCz,
    int K, float scale)
{
  int bx, by;
  if constexpr (MODE == 1) {
    const int i = blockIdx.x;
    by = (int)((__builtin_sqrtf(8.f * (float)i + 1.f) - 1.f) * 0.5f);
    if (((by * (by + 1)) >> 1) > i) by--;
    else if ((((by + 1) * (by + 2)) >> 1) <= i) by++;
    bx = i - ((by * (by + 1)) >> 1);
  } else {
    bx = blockIdx.x; by = blockIdx.y;
  }
  const int z = blockIdx.z;
  const int tri_by = (by * (by + 1)) >> 1;

  A += (size_t)z * sAz;
  B += (size_t)z * sBz;
  C += (size_t)z * sCz;

  int Klen = K;
  if (MODE == 2) Klen = min(K, (by + 1) * 256);
  const int NT = Klen >> 5;

  __shared__ short As[3][256 * 32];
  __shared__ short Bs[3][256 * 32];

  const int t = threadIdx.x;
  const int lane = t & 63;
  const int wave = t >> 6;
  const int wm = wave >> 2;
  const int wn = wave & 3;
  const int fr = lane & 15, kh = lane >> 4;
  const int koff = ((kh ^ ((fr >> 1) & 3)) << 3);

  int srow[2], scol[2];
  #pragma unroll
  for (int j = 0; j < 2; j++) {
    int e = j * 512 + t;
    srow[j] = e >> 2;
    scol[j] = (((e & 3) ^ ((e >> 3) & 3)) << 3);
  }

  f32x4 acc[8][4];
  #pragma unroll
  for (int i = 0; i < 8; i++)
    #pragma unroll
    for (int j = 0; j < 4; j++) acc[i][j] = (f32x4){0.f, 0.f, 0.f, 0.f};

  auto STAGE_A = [&](int kt) {
    const int buf = kt % 3, k0 = kt * 32;
    #pragma unroll
    for (int j = 0; j < 2; j++) {
      const short* pa;
      if constexpr (MODE == 2)
        pa = A + (size_t)(tri_by + (k0 >> 8)) * 65536 + (size_t)srow[j] * 256 + (k0 & 255) + scol[j];
      else
        pa = A + (size_t)(by * 256 + srow[j]) * lda + k0 + scol[j];
      GLDS(pa, (char*)&As[buf][0] + j * 8192 + wave * 1024);
    }
  };
  auto STAGE_B = [&](int kt) {
    const int buf = kt % 3, k0 = kt * 32;
    #pragma unroll
    for (int j = 0; j < 2; j++) {
      const short* pb = B + (size_t)(bx * 256 + srow[j]) * ldb + k0 + scol[j];
      GLDS(pb, (char*)&Bs[buf][0] + j * 8192 + wave * 1024);
    }
  };

  STAGE_A(0); STAGE_B(0);
  STAGE_A(1); STAGE_B(1);
  asm volatile("s_waitcnt vmcnt(4)\ns_barrier" ::: "memory");

  const int arow = wm * 128 + fr;
  const int brow = wn * 64 + fr;

  for (int kt = 0; kt < NT; kt++) {
    const short* as = &As[kt % 3][0];
    const short* bs = &Bs[kt % 3][0];
    short8 af[4], bfr[4];

    #pragma unroll
    for (int n = 0; n < 4; n++) bfr[n] = *(const short8*)&bs[(brow + n * 16) * 32 + koff];
    #pragma unroll
    for (int m = 0; m < 4; m++) af[m] = *(const short8*)&as[(arow + m * 16) * 32 + koff];
    if (kt + 2 < NT) STAGE_A(kt + 2);
    __builtin_amdgcn_s_barrier();
    asm volatile("s_waitcnt lgkmcnt(0)" ::: "memory");
    __builtin_amdgcn_sched_barrier(0);
    __builtin_amdgcn_s_setprio(1);
    #pragma unroll
    for (int m = 0; m < 4; m++)
      #pragma unroll
      for (int n = 0; n < 4; n++)
        acc[m][n] = __builtin_amdgcn_mfma_f32_16x16x32_bf16(af[m], bfr[n], acc[m][n], 0, 0, 0);
    __builtin_amdgcn_s_setprio(0);
    __builtin_amdgcn_sched_barrier(0);

    #pragma unroll
    for (int m = 0; m < 4; m++) af[m] = *(const short8*)&as[(arow + (m + 4) * 16) * 32 + koff];
    if (kt + 2 < NT) STAGE_B(kt + 2);
    __builtin_amdgcn_s_barrier();
    asm volatile("s_waitcnt lgkmcnt(0)" ::: "memory");
    __builtin_amdgcn_sched_barrier(0);
    __builtin_amdgcn_s_setprio(1);
    #pragma unroll
    for (int m = 0; m < 4; m++)
      #pragma unroll
      for (int n = 0; n < 4; n++)
        acc[m + 4][n] = __builtin_amdgcn_mfma_f32_16x16x32_bf16(af[m], bfr[n], acc[m + 4][n], 0, 0, 0);
    __builtin_amdgcn_s_setprio(0);
    __builtin_amdgcn_sched_barrier(0);

    if (kt + 2 < NT)      asm volatile("s_waitcnt vmcnt(4)\ns_barrier" ::: "memory");
    else if (kt + 1 < NT) asm volatile("s_waitcnt vmcnt(0)\ns_barrier" ::: "memory");
  }

  #pragma unroll
  for (int m = 0; m < 8; m++)
    #pragma unroll
    for (int n = 0; n < 4; n++) {
      int col_l = wn * 64 + n * 16 + fr;
      #pragma unroll
      for (int r = 0; r < 4; r++) {
        int row_l = wm * 128 + m * 16 + kh * 4 + r;
        if constexpr (MODE == 1)
          store_out(C, (size_t)(tri_by + bx) * 65536 + (size_t)row_l * 256 + col_l,
                    acc[m][n][r] * scale);
        else
          store_out(C, (size_t)(by * 256 + row_l) * ldc + bx * 256 + col_l,
                    acc[m][n][r] * scale);
      }
    }
}

// ---------------------------------------------------------------------------
// Small 128x128 GEMM (round-3 proven loop, linear LDS, no swizzle) — used
// only for the tiny W2T = Wk^T.Wq product (grid 8x8, K=1024).
// C[m][n] = scale * sum_k A[m][k]*B[n][k]
// ---------------------------------------------------------------------------
__global__ __launch_bounds__(256) void gemm128(
    const short* __restrict__ A, int lda,
    const short* __restrict__ B, int ldb,
    bf16* __restrict__ C, int ldc, int K, float scale)
{
  const int bx = blockIdx.x, by = blockIdx.y;
  __shared__ short a_lds[128 * 32];
  __shared__ short b_lds[128 * 32];

  const int t = threadIdx.x;
  const int lane = t & 63;
  const int wave = t >> 6;
  const int wm = wave >> 1, wn = wave & 1;
  const int fr = lane & 15, kh = lane >> 4;

  f32x4 acc[4][4];
  #pragma unroll
  for (int i = 0; i < 4; i++)
    #pragma unroll
    for (int j = 0; j < 4; j++) acc[i][j] = (f32x4){0.f, 0.f, 0.f, 0.f};

  for (int k0 = 0; k0 < K; k0 += 32) {
    #pragma unroll
    for (int i = 0; i < 2; i++) {
      int e = i * 256 + t;
      int r_ = e >> 2, c_ = (e & 3) * 8;
      GLDS(A + (size_t)(by * 128 + r_) * lda + k0 + c_, (char*)a_lds + i * 4096 + wave * 1024);
      GLDS(B + (size_t)(bx * 128 + r_) * ldb + k0 + c_, (char*)b_lds + i * 4096 + wave * 1024);
    }
    __syncthreads();

    short8 af[4], bfr[4];
    #pragma unroll
    for (int m = 0; m < 4; m++)
      af[m] = *(const short8*)&a_lds[(wm * 64 + m * 16 + fr) * 32 + kh * 8];
    #pragma unroll
    for (int n = 0; n < 4; n++)
      bfr[n] = *(const short8*)&b_lds[(wn * 64 + n * 16 + fr) * 32 + kh * 8];
    #pragma unroll
    for (int m = 0; m < 4; m++)
      #pragma unroll
      for (int n = 0; n < 4; n++)
        acc[m][n] = __builtin_amdgcn_mfma_f32_16x16x32_bf16(af[m], bfr[n], acc[m][n], 0, 0, 0);
    __syncthreads();
  }

  #pragma unroll
  for (int m = 0; m < 4; m++)
    #pragma unroll
    for (int n = 0; n < 4; n++) {
      int col = bx * 128 + wn * 64 + n * 16 + fr;
      #pragma unroll
      for (int r = 0; r < 4; r++) {
        int row = by * 128 + wm * 64 + m * 16 + kh * 4 + r;
        C[(size_t)row * ldc + col] = __float2bfloat16(acc[m][n][r] * scale);
      }
    }
}

// fp32 -> bf16 elementwise convert with scale
__global__ __launch_bounds__(256) void cvt_bf16(
    const float* __restrict__ in, bf16* __restrict__ out, int n, float scale)
{
  for (int i = (blockIdx.x * 256 + threadIdx.x) * 8; i < n; i += gridDim.x * 2048) {
    f32x4 v0 = *(const f32x4*)&in[i];
    f32x4 v1 = *(const f32x4*)&in[i + 4];
    short8 o = { f2bfbits(v0[0] * scale), f2bfbits(v0[1] * scale),
                 f2bfbits(v0[2] * scale), f2bfbits(v0[3] * scale),
                 f2bfbits(v1[0] * scale), f2bfbits(v1[1] * scale),
                 f2bfbits(v1[2] * scale), f2bfbits(v1[3] * scale) };
    *(short8*)&out[i] = o;
  }
}

// fp32 (N x N) -> bf16 transposed (N x N): out[c][r] = in[r][c]. 64x64 tiles.
__global__ __launch_bounds__(256) void cvt_t_bf16(
    const float* __restrict__ in, bf16* __restrict__ out, int N)
{
  __shared__ float tile[64][65];
  const int bx = blockIdx.x, by = blockIdx.y;
  const int t = threadIdx.x;
  #pragma unroll
  for (int i = 0; i < 16; i++) {
    int e = i * 256 + t;
    int r = e >> 6, c = e & 63;
    tile[r][c] = in[(size_t)(by * 64 + r) * N + bx * 64 + c];
  }
  __syncthreads();
  #pragma unroll
  for (int i = 0; i < 16; i++) {
    int e = i * 256 + t;
    int r = e >> 6, c = e & 63;
    out[(size_t)(bx * 64 + r) * N + by * 64 + c] = __float2bfloat16(tile[c][r]);
  }
}

// In-place softmax on 256-packed block-triangular bf16 scores.
__global__ __launch_bounds__(256) void softmax_causal_packed(short* SP, int T)
{
  __shared__ float rowv[4096];
  __shared__ float red[4];
  const int r = blockIdx.x;
  const int z = blockIdx.y;
  const int rb = r >> 8, rl = r & 255;
  const size_t tri = (size_t)((rb * (rb + 1)) >> 1);
  short* base = SP + (size_t)z * 136 * 65536;
  const int L = r + 1;
  const int kend = (rb + 1) * 256;
  const int t = threadIdx.x;

  float lmax = -3.0e38f;
  for (int i = t * 8; i < kend; i += 2048) {
    short8 s = *(const short8*)(base + (tri + (i >> 8)) * 65536 + (size_t)rl * 256 + (i & 255));
    #pragma unroll
    for (int j = 0; j < 8; j++) {
      float v = bf2f(s[j]);
      rowv[i + j] = v;
      if (i + j < L) lmax = fmaxf(lmax, v);
    }
  }
  #pragma unroll
  for (int o = 32; o > 0; o >>= 1) lmax = fmaxf(lmax, __shfl_down(lmax, o));
  if ((t & 63) == 0) red[t >> 6] = lmax;
  __syncthreads();
  const float m = fmaxf(fmaxf(red[0], red[1]), fmaxf(red[2], red[3]));
  __syncthreads();

  float lsum = 0.f;
  for (int i = t; i < kend; i += 256) {
    float e = (i < L) ? __expf(rowv[i] - m) : 0.f;
    rowv[i] = e;
    lsum += e;
  }
  #pragma unroll
  for (int o = 32; o > 0; o >>= 1) lsum += __shfl_down(lsum, o);
  if ((t & 63) == 0) red[t >> 6] = lsum;
  __syncthreads();
  const float inv = 1.f / (red[0] + red[1] + red[2] + red[3]);

  for (int i = t * 8; i < kend; i += 2048) {
    short8 o;
    #pragma unroll
    for (int j = 0; j < 8; j++) o[j] = f2bfbits(rowv[i + j] * inv);
    *(short8*)(base + (tri + (i >> 8)) * 65536 + (size_t)rl * 256 + (i & 255)) = o;
  }
}

extern "C" void kernel_launch(void* const* d_in, const int* in_sizes, int n_in,
                              void* d_out, int out_size, void* d_ws, size_t ws_size,
                              hipStream_t stream) {
  (void)in_sizes; (void)n_in; (void)out_size; (void)ws_size;
  const float* X  = (const float*)d_in[0];   // (B,T,E)
  const float* Wq = (const float*)d_in[1];   // (A,E)
  const float* Wk = (const float*)d_in[2];
  const float* Wv = (const float*)d_in[3];
  float* Out = (float*)d_out;                // (B,T,A) fp32

  const int Bn = 4, T = 4096, E = 1024, Ad = 1024;
  const int M = Bn * T;  // 16384

  // Algebra: S = X.(Wq^T Wk / 32).X^T  — K-projection eliminated (saves 34 GF)
  // workspace (peak ~172 MiB):
  //  [0,32Mi)    Q2  : M x 1024 bf16 = X . W2
  //  [32,64Mi)   Vt  : Ad x M bf16 (all-batch V^T)
  //  [64,96Mi)   Xb  : M x E bf16 (alive through S)
  //  [96,98Mi)   WqT : E x A bf16 (transposed)
  //  [98,100Mi)  WkT
  //  [100,102Mi) Wvb : (A,E) bf16
  //  [102,104Mi) W2T : (e2,e1) bf16 = Wk^T.Wq scaled 1/32
  //  [104Mi,+71.3MB) SP : 256-packed block-tri bf16, 4 x 136 x 256x256
  char* ws = (char*)d_ws;
  short* Q2  = (short*)ws;
  short* Vt  = (short*)(ws + 33554432);
  short* Xb  = (short*)(ws + 67108864);
  short* WqT = (short*)(ws + 100663296);
  short* WkT = (short*)(ws + 102760448);
  short* Wvb = (short*)(ws + 104857600);
  short* W2T = (short*)(ws + 106954752);
  short* SP  = (short*)(ws + 109051904);

  dim3 blk(256), blk5(512);
  const size_t SPz = (size_t)136 * 65536;

  // conversions
  cvt_bf16<<<dim3(8192), blk, 0, stream>>>(X, (bf16*)Xb, M * E, 1.0f);
  cvt_t_bf16<<<dim3(16, 16), blk, 0, stream>>>(Wq, (bf16*)WqT, E);
  cvt_t_bf16<<<dim3(16, 16), blk, 0, stream>>>(Wk, (bf16*)WkT, E);
  cvt_bf16<<<dim3(512), blk, 0, stream>>>(Wv, (bf16*)Wvb, Ad * E, 1.0f);

  // W2T[e2][e1] = sum_a Wk[a][e2]*Wq[a][e1] / 32   [grid 8x8, tiny]
  gemm128<<<dim3(8, 8), blk, 0, stream>>>(
      WkT, Ad, WqT, Ad, (bf16*)W2T, E, Ad, 0.03125f);

  // Q2 (M x 1024) = Xb . W2T^T   [grid 4 x 64]
  gemm256<bf16, 0><<<dim3(1024 / 256, M / 256), blk5, 0, stream>>>(
      Xb, E, 0, W2T, E, 0, (bf16*)Q2, 1024, 0, E, 1.0f);

  // all-batch V^T: Vt (Ad x M) = Wvb . Xb^T   [grid 64 x 4]
  gemm256<bf16, 0><<<dim3(M / 256, Ad / 256), blk5, 0, stream>>>(
      Wvb, E, 0, Xb, E, 0, (bf16*)Vt, M, 0, E, 1.0f);

  // S (256-packed tri, all batches) = Q2 . Xb^T   [tri grid 136 x 4]
  gemm256<bf16, 1><<<dim3(136, 1, Bn), blk5, 0, stream>>>(
      Q2, 1024, (size_t)T * 1024,
      Xb, 1024, (size_t)T * 1024,
      (bf16*)SP, 256, SPz, E, 1.0f);

  // in-place softmax on packed scores (all batches)
  softmax_causal_packed<<<dim3(T, Bn), blk, 0, stream>>>(SP, T);

  // O = P.V (256-packed P; causal K-limit)   [grid 4 x 16 x 4]
  gemm256<float, 2><<<dim3(Ad / 256, T / 256, Bn), blk5, 0, stream>>>(
      SP, 256, SPz,
      Vt, M, (size_t)T,
      Out, Ad, (size_t)T * Ad, T, 1.0f);
}